// Round 7
// baseline (561.489 us; speedup 1.0000x reference)
//
#include <hip/hip_runtime.h>
#include <hip/hip_bf16.h>

// Problem constants (fixed by the reference)
#define NN 50000      // nodes
#define EE 800000     // raw edges
#define TE 850000     // edges + self loops
#define NCH 196       // ceil(NN/256) chunks for the scan

typedef __hip_bfloat16 bf16;

__device__ __forceinline__ float b2f(bf16 v) { return __bfloat162float(v); }
__device__ __forceinline__ unsigned short f2bu(float v) {
    bf16 t = __float2bfloat16(v);
    return *(unsigned short*)&t;
}

// ---------------- runtime edge-index width detection ----------------
__global__ void detect_k(const unsigned int* __restrict__ eir, int* __restrict__ flags) {
    __shared__ int ci;
    int t = threadIdx.x;
    if (t == 0) ci = 0;
    __syncthreads();
    if (t < 64 && eir[2 * t + 1] == 0) atomicAdd(&ci, 1);
    __syncthreads();
    if (t == 0) flags[0] = (ci >= 32) ? 1 : 0;
}

__device__ __forceinline__ int load_edge(const void* ei, int isi64, long long idx) {
    int v = isi64 ? (int)((const long long*)ei)[idx] : ((const int*)ei)[idx];
    return (v < 0) ? 0 : (v >= NN ? NN - 1 : v);
}

// ---------------- CSR build (by dst) ----------------

__global__ void count_deg_k(const void* __restrict__ ei, const int* __restrict__ flags,
                            int* __restrict__ deg) {
    int i = blockIdx.x * 256 + threadIdx.x;
    if (i >= TE) return;
    int d = (i < EE) ? load_edge(ei, flags[0], (long long)EE + i) : (i - EE);
    atomicAdd(&deg[d], 1);
}

__global__ void scan_chunks_k(const int* __restrict__ deg, int* __restrict__ chunkoff) {
    __shared__ int s[256];
    int t = threadIdx.x;
    int sum = 0;
    if (t < NCH) {
        int base = t * 256;
        for (int j = 0; j < 256; ++j) {
            int idx = base + j;
            if (idx < NN) sum += deg[idx];
        }
    }
    s[t] = sum;
    __syncthreads();
    for (int d = 1; d < 256; d <<= 1) {
        int v = (t >= d) ? s[t - d] : 0;
        __syncthreads();
        s[t] += v;
        __syncthreads();
    }
    if (t < NCH) chunkoff[t] = s[t] - sum;
}

__global__ void scan_within_k(const int* __restrict__ deg, const int* __restrict__ chunkoff,
                              int* __restrict__ offs) {
    __shared__ int s[256];
    int t = threadIdx.x, b = blockIdx.x, i = b * 256 + t;
    int v = (i < NN) ? deg[i] : 0;
    s[t] = v;
    __syncthreads();
    for (int d = 1; d < 256; d <<= 1) {
        int u = (t >= d) ? s[t - d] : 0;
        __syncthreads();
        s[t] += u;
        __syncthreads();
    }
    if (i < NN) offs[i] = chunkoff[b] + s[t] - v;
    if (i == NN - 1) offs[NN] = chunkoff[b] + s[t];
}

__global__ void fill_csr_k(const void* __restrict__ ei, const int* __restrict__ flags,
                           const int* __restrict__ offs,
                           int* __restrict__ cursor, int* __restrict__ csr_src) {
    int i = blockIdx.x * 256 + threadIdx.x;
    if (i >= TE) return;
    int sdx, d;
    if (i < EE) {
        int isi64 = flags[0];
        sdx = load_edge(ei, isi64, i);
        d   = load_edge(ei, isi64, (long long)EE + i);
    } else {
        sdx = i - EE; d = i - EE;
    }
    int pos = offs[d] + atomicAdd(&cursor[d], 1);
    csr_src[pos] = sdx;
}

// Deterministic order: sort each dst bucket ascending. Atomic fill order is
// nondeterministic; sorted buckets are unique -> bit-stable output every call
// (required by the harness's post-timing re-validation).
__global__ void sort_csr_k(const int* __restrict__ offs, int* __restrict__ csr_src) {
    int dst = blockIdx.x * 256 + threadIdx.x;
    if (dst >= NN) return;
    int s = offs[dst], e = offs[dst + 1];
    for (int i = s + 1; i < e; ++i) {
        int v = csr_src[i];
        int j = i - 1;
        while (j >= s && csr_src[j] > v) { csr_src[j + 1] = csr_src[j]; --j; }
        csr_src[j + 1] = v;
    }
}

// ---------------- Layer 1 GEMM: h1 = x@W1 (bf16 out) + alpha partials -------
// block 256 = 32 rows x 256 cols; thread = 4 cols x 8 rows
__global__ __launch_bounds__(256) void gemm1_k(
    const float* __restrict__ x, const float* __restrict__ W1,
    const float* __restrict__ asr, const float* __restrict__ ads,
    bf16* __restrict__ h1, float* __restrict__ a_src, float* __restrict__ a_dst) {
    __shared__ float4 xs4[32 * 32];
    int tid = threadIdx.x;
    int base = blockIdx.x * 32;
    const float4* x4 = (const float4*)x;
    for (int i = tid; i < 1024; i += 256) {
        int row = base + (i >> 5);
        xs4[i] = (row < NN) ? x4[(size_t)base * 32 + i] : make_float4(0.f, 0.f, 0.f, 0.f);
    }
    __syncthreads();
    int cg = tid & 63, rg = tid >> 6;
    int c0 = cg * 4;
    float4 acc[8];
#pragma unroll
    for (int r = 0; r < 8; ++r) acc[r] = make_float4(0.f, 0.f, 0.f, 0.f);
    for (int kq = 0; kq < 32; ++kq) {
        float4 w0 = *(const float4*)&W1[(kq * 4 + 0) * 256 + c0];
        float4 w1 = *(const float4*)&W1[(kq * 4 + 1) * 256 + c0];
        float4 w2 = *(const float4*)&W1[(kq * 4 + 2) * 256 + c0];
        float4 w3 = *(const float4*)&W1[(kq * 4 + 3) * 256 + c0];
#pragma unroll
        for (int r = 0; r < 8; ++r) {
            float4 xv = xs4[(rg * 8 + r) * 32 + kq];
            acc[r].x += xv.x * w0.x + xv.y * w1.x + xv.z * w2.x + xv.w * w3.x;
            acc[r].y += xv.x * w0.y + xv.y * w1.y + xv.z * w2.y + xv.w * w3.y;
            acc[r].z += xv.x * w0.z + xv.y * w1.z + xv.z * w2.z + xv.w * w3.z;
            acc[r].w += xv.x * w0.w + xv.y * w1.w + xv.z * w2.w + xv.w * w3.w;
        }
    }
    int h = cg >> 2;
    float sa0 = asr[c0], sa1 = asr[c0 + 1], sa2 = asr[c0 + 2], sa3 = asr[c0 + 3];
    float da0 = ads[c0], da1 = ads[c0 + 1], da2 = ads[c0 + 2], da3 = ads[c0 + 3];
#pragma unroll
    for (int r = 0; r < 8; ++r) {
        int row = base + rg * 8 + r;
        if (row < NN) {
            ushort4 st;
            st.x = f2bu(acc[r].x); st.y = f2bu(acc[r].y);
            st.z = f2bu(acc[r].z); st.w = f2bu(acc[r].w);
            *(ushort4*)&h1[(size_t)row * 256 + c0] = st;
            float ps = acc[r].x * sa0 + acc[r].y * sa1 + acc[r].z * sa2 + acc[r].w * sa3;
            float pd = acc[r].x * da0 + acc[r].y * da1 + acc[r].z * da2 + acc[r].w * da3;
            ps += __shfl_xor(ps, 1, 64); ps += __shfl_xor(ps, 2, 64);
            pd += __shfl_xor(pd, 1, 64); pd += __shfl_xor(pd, 2, 64);
            if ((cg & 3) == 0) {
                a_src[row * 16 + h] = ps;
                a_dst[row * 16 + h] = pd;
            }
        }
    }
}

// ---------------- Layer 1 aggregation: raw-softmax gather-sum ---------------
// block 256 = one dst. Weight role: head=tid&15, edge-slot=tid>>4 (16-edge tiles).
// Consumer role: channel=tid, head=tid>>4. Raw exp weights; divide at end.
__global__ __launch_bounds__(256) void agg1_k(
    const int* __restrict__ offs, const int* __restrict__ csr_src,
    const float* __restrict__ a_src, const float* __restrict__ a_dst,
    const bf16* __restrict__ h1, const float* __restrict__ b1,
    bf16* __restrict__ out1) {
    int dst = blockIdx.x;
    int tid = threadIdx.x;
    int start = offs[dst], end = offs[dst + 1];
    int wh = tid & 15;        // weight-role head
    int we = tid >> 4;        // weight-role edge slot
    int h  = tid >> 4;        // consumer-role head
    float adst_w = a_dst[dst * 16 + wh];
    __shared__ int2 wsl[16 * 16];     // {src, w-bits} per (edge-slot, head)
    __shared__ float part[256];
    __shared__ float invd[16];
    float dsum = 0.f;
    float acc = 0.f;
    for (int t0 = start; t0 < end; t0 += 16) {
        int n = end - t0; if (n > 16) n = 16;
        if (we < n) {
            int s = csr_src[t0 + we];
            float e = a_src[s * 16 + wh] + adst_w;
            e = (e > 0.f) ? e : 0.2f * e;
            float w = __expf(e);
            dsum += w;
            wsl[we * 16 + wh] = make_int2(s, __float_as_int(w));
        }
        __syncthreads();
        for (int j = 0; j < n; ++j) {
            int2 p = wsl[j * 16 + h];
            float w = __int_as_float(p.y);
            acc += w * b2f(h1[(size_t)p.x * 256 + tid]);
        }
        __syncthreads();
    }
    part[tid] = dsum;
    __syncthreads();
    if (tid < 16) {
        float d = 0.f;
#pragma unroll
        for (int e2 = 0; e2 < 16; ++e2) d += part[e2 * 16 + tid];
        invd[tid] = 1.f / (d + 1e-16f);
    }
    __syncthreads();
    out1[(size_t)dst * 256 + tid] = __float2bfloat16(acc * invd[h] + b1[tid]);
}

// ---------------- Layer 2 GEMM: h2 = out1@W2 (bf16 out) + alpha2 ------------
__global__ __launch_bounds__(256) void gemm2_k(
    const bf16* __restrict__ out1, const float* __restrict__ W2,
    const float* __restrict__ asr2, const float* __restrict__ ads2,
    bf16* __restrict__ h2, float* __restrict__ a_src2, float* __restrict__ a_dst2) {
    __shared__ bf16 ys[64 * 256];   // 32 KB
    int tid = threadIdx.x;
    int base = blockIdx.x * 64;
    uint4* ys16 = (uint4*)ys;
    const uint4* in16 = (const uint4*)out1;
    for (int i = tid; i < 2048; i += 256) {
        int row = base + (i >> 5);
        uint4 z; z.x = z.y = z.z = z.w = 0u;
        ys16[i] = (row < NN) ? in16[(size_t)base * 32 + i] : z;
    }
    __syncthreads();
    int cg = tid & 31, rg = tid >> 5;
    int c0 = cg * 2;
    float2 acc[8];
#pragma unroll
    for (int r = 0; r < 8; ++r) acc[r] = make_float2(0.f, 0.f);
    for (int kq = 0; kq < 64; ++kq) {
        float2 w0 = *(const float2*)&W2[(kq * 4 + 0) * 64 + c0];
        float2 w1 = *(const float2*)&W2[(kq * 4 + 1) * 64 + c0];
        float2 w2 = *(const float2*)&W2[(kq * 4 + 2) * 64 + c0];
        float2 w3 = *(const float2*)&W2[(kq * 4 + 3) * 64 + c0];
#pragma unroll
        for (int r = 0; r < 8; ++r) {
            const __hip_bfloat162* yp =
                (const __hip_bfloat162*)&ys[(rg * 8 + r) * 256 + kq * 4];
            float2 y01 = __bfloat1622float2(yp[0]);
            float2 y23 = __bfloat1622float2(yp[1]);
            acc[r].x += y01.x * w0.x + y01.y * w1.x + y23.x * w2.x + y23.y * w3.x;
            acc[r].y += y01.x * w0.y + y01.y * w1.y + y23.x * w2.y + y23.y * w3.y;
        }
    }
    float sa0 = asr2[c0], sa1 = asr2[c0 + 1];
    float da0 = ads2[c0], da1 = ads2[c0 + 1];
#pragma unroll
    for (int r = 0; r < 8; ++r) {
        int row = base + rg * 8 + r;
        if (row < NN) {
            __hip_bfloat162 hb;
            hb.x = __float2bfloat16(acc[r].x);
            hb.y = __float2bfloat16(acc[r].y);
            *(__hip_bfloat162*)&h2[(size_t)row * 64 + c0] = hb;
            float ps = acc[r].x * sa0 + acc[r].y * sa1;
            float pd = acc[r].x * da0 + acc[r].y * da1;
#pragma unroll
            for (int o = 1; o <= 16; o <<= 1) {
                ps += __shfl_xor(ps, o, 64);
                pd += __shfl_xor(pd, o, 64);
            }
            if (cg == 0) { a_src2[row] = ps; a_dst2[row] = pd; }
        }
    }
}

// ---------------- Layer 2 aggregation + sigmoid (f32 out) -------------------
// block 256 = 4 dst (one wave each); lane = channel. Wave-cooperative weights.
__global__ __launch_bounds__(256) void agg2_k(
    const int* __restrict__ offs, const int* __restrict__ csr_src,
    const float* __restrict__ a_src2, const float* __restrict__ a_dst2,
    const bf16* __restrict__ h2, const float* __restrict__ b2,
    float* __restrict__ out) {
    int wv = threadIdx.x >> 6;
    int lane = threadIdx.x & 63;
    int dst = blockIdx.x * 4 + wv;
    if (dst >= NN) return;
    int start = offs[dst], end = offs[dst + 1];
    float adst = a_dst2[dst];
    float acc = 0.f, dsum = 0.f;
    for (int t0 = start; t0 < end; t0 += 64) {
        int n = end - t0; if (n > 64) n = 64;
        float wr = 0.f; int sr = 0;
        if (lane < n) {
            sr = csr_src[t0 + lane];
            float e = a_src2[sr] + adst;
            e = (e > 0.f) ? e : 0.2f * e;
            wr = __expf(e);
        }
        dsum += wr;
        for (int j = 0; j < n; ++j) {
            float wj = __shfl(wr, j, 64);
            int sj = __shfl(sr, j, 64);
            acc += wj * b2f(h2[(size_t)sj * 64 + lane]);
        }
    }
#pragma unroll
    for (int o = 32; o >= 1; o >>= 1) dsum += __shfl_xor(dsum, o, 64);
    float o = acc / (dsum + 1e-16f) + b2[lane];
    out[(size_t)dst * 64 + lane] = 1.f / (1.f + __expf(-o));
}

// ---------------- host ------------------------------------------------------

extern "C" void kernel_launch(void* const* d_in, const int* in_sizes, int n_in,
                              void* d_out, int out_size, void* d_ws, size_t ws_size,
                              hipStream_t stream) {
    const float* x    = (const float*)d_in[0];
    const void*  ei   = d_in[1];
    const float* W1   = (const float*)d_in[2];
    const float* asr1 = (const float*)d_in[3];
    const float* ads1 = (const float*)d_in[4];
    const float* b1   = (const float*)d_in[5];
    const float* W2   = (const float*)d_in[6];
    const float* asr2 = (const float*)d_in[7];
    const float* ads2 = (const float*)d_in[8];
    const float* b2   = (const float*)d_in[9];
    float* out = (float*)d_out;

    char* w = (char*)d_ws;
    auto carve = [&](size_t bytes) {
        void* p = (void*)w;
        w += (bytes + 255) & ~(size_t)255;
        return p;
    };
    int*    flags    = (int*)carve(256);
    int*    csr_src  = (int*)carve((size_t)TE * 4);            // 3.4 MB
    int*    offs     = (int*)carve((size_t)(NN + 1) * 4);
    int*    deg      = (int*)carve((size_t)NN * 4);
    int*    cursor   = (int*)carve((size_t)NN * 4);
    int*    chunkoff = (int*)carve(256 * 4);
    float*  a_src1   = (float*)carve((size_t)NN * 16 * 4);     // 3.2 MB
    float*  a_dst1   = (float*)carve((size_t)NN * 16 * 4);     // 3.2 MB
    bf16*   h1       = (bf16*)carve((size_t)NN * 256 * 2);     // 25.6 MB
    bf16*   out1     = (bf16*)carve((size_t)NN * 256 * 2);     // 25.6 MB
    // layer-2 buffers alias h1 (dead after agg1)
    char*   l2base   = (char*)h1;
    bf16*   h2       = (bf16*)l2base;                          // 6.4 MB
    float*  a_src2   = (float*)(l2base + (size_t)NN * 64 * 2);
    float*  a_dst2   = a_src2 + NN;

    hipMemsetAsync(deg, 0, (size_t)NN * 4, stream);
    hipMemsetAsync(cursor, 0, (size_t)NN * 4, stream);

    detect_k<<<1, 256, 0, stream>>>((const unsigned int*)ei, flags);

    const int egrid = (TE + 255) / 256;
    count_deg_k<<<egrid, 256, 0, stream>>>(ei, flags, deg);
    scan_chunks_k<<<1, 256, 0, stream>>>(deg, chunkoff);
    scan_within_k<<<NCH, 256, 0, stream>>>(deg, chunkoff, offs);
    fill_csr_k<<<egrid, 256, 0, stream>>>(ei, flags, offs, cursor, csr_src);
    sort_csr_k<<<NCH, 256, 0, stream>>>(offs, csr_src);

    gemm1_k<<<(NN + 31) / 32, 256, 0, stream>>>(x, W1, asr1, ads1, h1, a_src1, a_dst1);
    agg1_k<<<NN, 256, 0, stream>>>(offs, csr_src, a_src1, a_dst1, h1, b1, out1);
    gemm2_k<<<(NN + 63) / 64, 256, 0, stream>>>(out1, W2, asr2, ads2, h2, a_src2, a_dst2);
    agg2_k<<<(NN + 3) / 4, 256, 0, stream>>>(offs, csr_src, a_src2, a_dst2, h2, b2, out);
}

// Round 8
// 457.105 us; speedup vs baseline: 1.2284x; 1.2284x over previous
//
#include <hip/hip_runtime.h>
#include <hip/hip_bf16.h>

// Problem constants (fixed by the reference)
#define NN 50000      // nodes
#define EE 800000     // raw edges
#define TE 850000     // edges + self loops
#define NCH 196       // ceil(NN/256) chunks for the scan

typedef __hip_bfloat16 bf16;

__device__ __forceinline__ float b2f(bf16 v) { return __bfloat162float(v); }
__device__ __forceinline__ float bu2f(unsigned short v) {
    return __uint_as_float((unsigned)v << 16);
}
__device__ __forceinline__ unsigned short f2bu(float v) {
    bf16 t = __float2bfloat16(v);
    return *(unsigned short*)&t;
}

// ---------------- runtime edge-index width detection ----------------
__global__ void detect_k(const unsigned int* __restrict__ eir, int* __restrict__ flags) {
    __shared__ int ci;
    int t = threadIdx.x;
    if (t == 0) ci = 0;
    __syncthreads();
    if (t < 64 && eir[2 * t + 1] == 0) atomicAdd(&ci, 1);
    __syncthreads();
    if (t == 0) flags[0] = (ci >= 32) ? 1 : 0;
}

__device__ __forceinline__ int load_edge(const void* ei, int isi64, long long idx) {
    int v = isi64 ? (int)((const long long*)ei)[idx] : ((const int*)ei)[idx];
    return (v < 0) ? 0 : (v >= NN ? NN - 1 : v);
}

// ---------------- CSR build (by dst) ----------------

__global__ void count_deg_k(const void* __restrict__ ei, const int* __restrict__ flags,
                            int* __restrict__ deg) {
    int i = blockIdx.x * 256 + threadIdx.x;
    if (i >= TE) return;
    int d = (i < EE) ? load_edge(ei, flags[0], (long long)EE + i) : (i - EE);
    atomicAdd(&deg[d], 1);
}

__global__ void scan_chunks_k(const int* __restrict__ deg, int* __restrict__ chunkoff) {
    __shared__ int s[256];
    int t = threadIdx.x;
    int sum = 0;
    if (t < NCH) {
        const int4* d4 = (const int4*)(deg + t * 256);
        int lim = (t == NCH - 1) ? (NN - t * 256) : 256;   // last chunk is short (NN%256=80)
        int i = 0;
        for (; i + 4 <= lim; i += 4) {
            int4 v = d4[i >> 2];
            sum += v.x + v.y + v.z + v.w;
        }
        for (; i < lim; ++i) sum += deg[t * 256 + i];
    }
    s[t] = sum;
    __syncthreads();
    for (int d = 1; d < 256; d <<= 1) {
        int v = (t >= d) ? s[t - d] : 0;
        __syncthreads();
        s[t] += v;
        __syncthreads();
    }
    if (t < NCH) chunkoff[t] = s[t] - sum;
}

__global__ void scan_within_k(const int* __restrict__ deg, const int* __restrict__ chunkoff,
                              int* __restrict__ offs) {
    __shared__ int s[256];
    int t = threadIdx.x, b = blockIdx.x, i = b * 256 + t;
    int v = (i < NN) ? deg[i] : 0;
    s[t] = v;
    __syncthreads();
    for (int d = 1; d < 256; d <<= 1) {
        int u = (t >= d) ? s[t - d] : 0;
        __syncthreads();
        s[t] += u;
        __syncthreads();
    }
    if (i < NN) offs[i] = chunkoff[b] + s[t] - v;
    if (i == NN - 1) offs[NN] = chunkoff[b] + s[t];
}

__global__ void fill_csr_k(const void* __restrict__ ei, const int* __restrict__ flags,
                           const int* __restrict__ offs,
                           int* __restrict__ cursor, int* __restrict__ csr_src) {
    int i = blockIdx.x * 256 + threadIdx.x;
    if (i >= TE) return;
    int sdx, d;
    if (i < EE) {
        int isi64 = flags[0];
        sdx = load_edge(ei, isi64, i);
        d   = load_edge(ei, isi64, (long long)EE + i);
    } else {
        sdx = i - EE; d = i - EE;
    }
    int pos = offs[d] + atomicAdd(&cursor[d], 1);
    csr_src[pos] = sdx;
}

// Deterministic order: sort each dst bucket ascending (multiset -> unique array,
// so atomic arrival order can't leak through). LDS-staged insertion sort,
// transposed layout buf[i*64+t]: lane t -> bank t%32, 2-way conflict = free.
#define SCAP 96
__global__ __launch_bounds__(64) void sort_csr_k(const int* __restrict__ offs,
                                                 int* __restrict__ csr_src) {
    __shared__ int buf[SCAP * 64];
    int t = threadIdx.x;
    int dst = blockIdx.x * 64 + t;
    if (dst >= NN) return;
    int s = offs[dst], e = offs[dst + 1];
    int d = e - s;
    if (d <= SCAP) {
        for (int i = 0; i < d; ++i) buf[i * 64 + t] = csr_src[s + i];
        for (int i = 1; i < d; ++i) {
            int v = buf[i * 64 + t];
            int j = i - 1;
            while (j >= 0 && buf[j * 64 + t] > v) {
                buf[(j + 1) * 64 + t] = buf[j * 64 + t]; --j;
            }
            buf[(j + 1) * 64 + t] = v;
        }
        for (int i = 0; i < d; ++i) csr_src[s + i] = buf[i * 64 + t];
    } else {                       // rare deep bucket: in-place global sort
        for (int i = s + 1; i < e; ++i) {
            int v = csr_src[i];
            int j = i - 1;
            while (j >= s && csr_src[j] > v) { csr_src[j + 1] = csr_src[j]; --j; }
            csr_src[j + 1] = v;
        }
    }
}

// ---------------- Layer 1 GEMM: h1 = x@W1 (bf16 out) + alpha partials -------
// block 256 = 32 rows x 256 cols; thread = 4 cols x 8 rows
__global__ __launch_bounds__(256) void gemm1_k(
    const float* __restrict__ x, const float* __restrict__ W1,
    const float* __restrict__ asr, const float* __restrict__ ads,
    bf16* __restrict__ h1, float* __restrict__ a_src, float* __restrict__ a_dst) {
    __shared__ float4 xs4[32 * 32];
    int tid = threadIdx.x;
    int base = blockIdx.x * 32;
    const float4* x4 = (const float4*)x;
    for (int i = tid; i < 1024; i += 256) {
        int row = base + (i >> 5);
        xs4[i] = (row < NN) ? x4[(size_t)base * 32 + i] : make_float4(0.f, 0.f, 0.f, 0.f);
    }
    __syncthreads();
    int cg = tid & 63, rg = tid >> 6;
    int c0 = cg * 4;
    float4 acc[8];
#pragma unroll
    for (int r = 0; r < 8; ++r) acc[r] = make_float4(0.f, 0.f, 0.f, 0.f);
    for (int kq = 0; kq < 32; ++kq) {
        float4 w0 = *(const float4*)&W1[(kq * 4 + 0) * 256 + c0];
        float4 w1 = *(const float4*)&W1[(kq * 4 + 1) * 256 + c0];
        float4 w2 = *(const float4*)&W1[(kq * 4 + 2) * 256 + c0];
        float4 w3 = *(const float4*)&W1[(kq * 4 + 3) * 256 + c0];
#pragma unroll
        for (int r = 0; r < 8; ++r) {
            float4 xv = xs4[(rg * 8 + r) * 32 + kq];
            acc[r].x += xv.x * w0.x + xv.y * w1.x + xv.z * w2.x + xv.w * w3.x;
            acc[r].y += xv.x * w0.y + xv.y * w1.y + xv.z * w2.y + xv.w * w3.y;
            acc[r].z += xv.x * w0.z + xv.y * w1.z + xv.z * w2.z + xv.w * w3.z;
            acc[r].w += xv.x * w0.w + xv.y * w1.w + xv.z * w2.w + xv.w * w3.w;
        }
    }
    int h = cg >> 2;
    float sa0 = asr[c0], sa1 = asr[c0 + 1], sa2 = asr[c0 + 2], sa3 = asr[c0 + 3];
    float da0 = ads[c0], da1 = ads[c0 + 1], da2 = ads[c0 + 2], da3 = ads[c0 + 3];
#pragma unroll
    for (int r = 0; r < 8; ++r) {
        int row = base + rg * 8 + r;
        if (row < NN) {
            ushort4 st;
            st.x = f2bu(acc[r].x); st.y = f2bu(acc[r].y);
            st.z = f2bu(acc[r].z); st.w = f2bu(acc[r].w);
            *(ushort4*)&h1[(size_t)row * 256 + c0] = st;
            float ps = acc[r].x * sa0 + acc[r].y * sa1 + acc[r].z * sa2 + acc[r].w * sa3;
            float pd = acc[r].x * da0 + acc[r].y * da1 + acc[r].z * da2 + acc[r].w * da3;
            ps += __shfl_xor(ps, 1, 64); ps += __shfl_xor(ps, 2, 64);
            pd += __shfl_xor(pd, 1, 64); pd += __shfl_xor(pd, 2, 64);
            if ((cg & 3) == 0) {
                a_src[row * 16 + h] = ps;
                a_dst[row * 16 + h] = pd;
            }
        }
    }
}

// ---------------- Layer 1 aggregation: wave-per-dst, barrier-free -----------
// Wave = one dst. Lane owns channels 4*lane..4*lane+3 (head hc = lane>>2).
// Weight role per 4-edge tile: lane = (edge-slot we = lane>>4, head wh = lane&15)
// computes exp once; consumers pull via shfl. Raw-exp softmax, divide at end.
__global__ __launch_bounds__(256) void agg1_k(
    const int* __restrict__ offs, const int* __restrict__ csr_src,
    const float* __restrict__ a_src, const float* __restrict__ a_dst,
    const bf16* __restrict__ h1, const float* __restrict__ b1,
    bf16* __restrict__ out1) {
    int wv = threadIdx.x >> 6, lane = threadIdx.x & 63;
    int dst = blockIdx.x * 4 + wv;          // grid = NN/4 exactly
    int start = offs[dst], end = offs[dst + 1];
    int we = lane >> 4, wh = lane & 15;     // weight role
    int hc = lane >> 2;                      // consumer head
    float adst_w = a_dst[dst * 16 + wh];
    float ax = 0.f, ay = 0.f, az = 0.f, aw = 0.f;
    float dsum = 0.f;
    int t0 = start;
    for (; t0 + 4 <= end; t0 += 4) {
        int sr = csr_src[t0 + we];
        float e = a_src[sr * 16 + wh] + adst_w;
        e = (e > 0.f) ? e : 0.2f * e;
        float wr = __expf(e);
        dsum += wr;
#pragma unroll
        for (int j = 0; j < 4; ++j) {
            int sl = j * 16 + hc;
            float wj = __shfl(wr, sl, 64);
            int sj = __shfl(sr, sl, 64);
            ushort4 hv = *(const ushort4*)&h1[(size_t)sj * 256 + lane * 4];
            ax += wj * bu2f(hv.x);
            ay += wj * bu2f(hv.y);
            az += wj * bu2f(hv.z);
            aw += wj * bu2f(hv.w);
        }
    }
    if (t0 < end) {
        int n = end - t0;
        float wr = 0.f; int sr = 0;
        if (we < n) {
            sr = csr_src[t0 + we];
            float e = a_src[sr * 16 + wh] + adst_w;
            e = (e > 0.f) ? e : 0.2f * e;
            wr = __expf(e);
        }
        dsum += wr;
        for (int j = 0; j < n; ++j) {
            int sl = j * 16 + hc;
            float wj = __shfl(wr, sl, 64);
            int sj = __shfl(sr, sl, 64);
            ushort4 hv = *(const ushort4*)&h1[(size_t)sj * 256 + lane * 4];
            ax += wj * bu2f(hv.x);
            ay += wj * bu2f(hv.y);
            az += wj * bu2f(hv.z);
            aw += wj * bu2f(hv.w);
        }
    }
    // reduce dsum over the 4 edge-slots: lane l then holds total for head l&15
    dsum += __shfl_xor(dsum, 16, 64);
    dsum += __shfl_xor(dsum, 32, 64);
    float invd = 1.f / (__shfl(dsum, hc, 64) + 1e-16f);
    float4 bv = *(const float4*)&b1[lane * 4];
    ushort4 st;
    st.x = f2bu(ax * invd + bv.x);
    st.y = f2bu(ay * invd + bv.y);
    st.z = f2bu(az * invd + bv.z);
    st.w = f2bu(aw * invd + bv.w);
    *(ushort4*)&out1[(size_t)dst * 256 + lane * 4] = st;
}

// ---------------- Layer 2 GEMM: h2 = out1@W2 (bf16 out) + alpha2 ------------
__global__ __launch_bounds__(256) void gemm2_k(
    const bf16* __restrict__ out1, const float* __restrict__ W2,
    const float* __restrict__ asr2, const float* __restrict__ ads2,
    bf16* __restrict__ h2, float* __restrict__ a_src2, float* __restrict__ a_dst2) {
    __shared__ bf16 ys[64 * 256];   // 32 KB
    int tid = threadIdx.x;
    int base = blockIdx.x * 64;
    uint4* ys16 = (uint4*)ys;
    const uint4* in16 = (const uint4*)out1;
    for (int i = tid; i < 2048; i += 256) {
        int row = base + (i >> 5);
        uint4 z; z.x = z.y = z.z = z.w = 0u;
        ys16[i] = (row < NN) ? in16[(size_t)base * 32 + i] : z;
    }
    __syncthreads();
    int cg = tid & 31, rg = tid >> 5;
    int c0 = cg * 2;
    float2 acc[8];
#pragma unroll
    for (int r = 0; r < 8; ++r) acc[r] = make_float2(0.f, 0.f);
    for (int kq = 0; kq < 64; ++kq) {
        float2 w0 = *(const float2*)&W2[(kq * 4 + 0) * 64 + c0];
        float2 w1 = *(const float2*)&W2[(kq * 4 + 1) * 64 + c0];
        float2 w2 = *(const float2*)&W2[(kq * 4 + 2) * 64 + c0];
        float2 w3 = *(const float2*)&W2[(kq * 4 + 3) * 64 + c0];
#pragma unroll
        for (int r = 0; r < 8; ++r) {
            const __hip_bfloat162* yp =
                (const __hip_bfloat162*)&ys[(rg * 8 + r) * 256 + kq * 4];
            float2 y01 = __bfloat1622float2(yp[0]);
            float2 y23 = __bfloat1622float2(yp[1]);
            acc[r].x += y01.x * w0.x + y01.y * w1.x + y23.x * w2.x + y23.y * w3.x;
            acc[r].y += y01.x * w0.y + y01.y * w1.y + y23.x * w2.y + y23.y * w3.y;
        }
    }
    float sa0 = asr2[c0], sa1 = asr2[c0 + 1];
    float da0 = ads2[c0], da1 = ads2[c0 + 1];
#pragma unroll
    for (int r = 0; r < 8; ++r) {
        int row = base + rg * 8 + r;
        if (row < NN) {
            __hip_bfloat162 hb;
            hb.x = __float2bfloat16(acc[r].x);
            hb.y = __float2bfloat16(acc[r].y);
            *(__hip_bfloat162*)&h2[(size_t)row * 64 + c0] = hb;
            float ps = acc[r].x * sa0 + acc[r].y * sa1;
            float pd = acc[r].x * da0 + acc[r].y * da1;
#pragma unroll
            for (int o = 1; o <= 16; o <<= 1) {
                ps += __shfl_xor(ps, o, 64);
                pd += __shfl_xor(pd, o, 64);
            }
            if (cg == 0) { a_src2[row] = ps; a_dst2[row] = pd; }
        }
    }
}

// ---------------- Layer 2 aggregation + sigmoid (f32 out) -------------------
// block 256 = 4 dst (one wave each); lane = channel. Wave-cooperative weights.
__global__ __launch_bounds__(256) void agg2_k(
    const int* __restrict__ offs, const int* __restrict__ csr_src,
    const float* __restrict__ a_src2, const float* __restrict__ a_dst2,
    const bf16* __restrict__ h2, const float* __restrict__ b2,
    float* __restrict__ out) {
    int wv = threadIdx.x >> 6;
    int lane = threadIdx.x & 63;
    int dst = blockIdx.x * 4 + wv;
    if (dst >= NN) return;
    int start = offs[dst], end = offs[dst + 1];
    float adst = a_dst2[dst];
    float acc = 0.f, dsum = 0.f;
    for (int t0 = start; t0 < end; t0 += 64) {
        int n = end - t0; if (n > 64) n = 64;
        float wr = 0.f; int sr = 0;
        if (lane < n) {
            sr = csr_src[t0 + lane];
            float e = a_src2[sr] + adst;
            e = (e > 0.f) ? e : 0.2f * e;
            wr = __expf(e);
        }
        dsum += wr;
        for (int j = 0; j < n; ++j) {
            float wj = __shfl(wr, j, 64);
            int sj = __shfl(sr, j, 64);
            acc += wj * b2f(h2[(size_t)sj * 64 + lane]);
        }
    }
#pragma unroll
    for (int o = 32; o >= 1; o >>= 1) dsum += __shfl_xor(dsum, o, 64);
    float o = acc / (dsum + 1e-16f) + b2[lane];
    out[(size_t)dst * 64 + lane] = 1.f / (1.f + __expf(-o));
}

// ---------------- host ------------------------------------------------------

extern "C" void kernel_launch(void* const* d_in, const int* in_sizes, int n_in,
                              void* d_out, int out_size, void* d_ws, size_t ws_size,
                              hipStream_t stream) {
    const float* x    = (const float*)d_in[0];
    const void*  ei   = d_in[1];
    const float* W1   = (const float*)d_in[2];
    const float* asr1 = (const float*)d_in[3];
    const float* ads1 = (const float*)d_in[4];
    const float* b1   = (const float*)d_in[5];
    const float* W2   = (const float*)d_in[6];
    const float* asr2 = (const float*)d_in[7];
    const float* ads2 = (const float*)d_in[8];
    const float* b2   = (const float*)d_in[9];
    float* out = (float*)d_out;

    char* w = (char*)d_ws;
    auto carve = [&](size_t bytes) {
        void* p = (void*)w;
        w += (bytes + 255) & ~(size_t)255;
        return p;
    };
    int*    flags    = (int*)carve(256);
    int*    csr_src  = (int*)carve((size_t)TE * 4);            // 3.4 MB
    int*    offs     = (int*)carve((size_t)(NN + 1) * 4);
    int*    deg      = (int*)carve((size_t)NN * 4);
    int*    cursor   = (int*)carve((size_t)NN * 4);
    int*    chunkoff = (int*)carve(256 * 4);
    float*  a_src1   = (float*)carve((size_t)NN * 16 * 4);     // 3.2 MB
    float*  a_dst1   = (float*)carve((size_t)NN * 16 * 4);     // 3.2 MB
    bf16*   h1       = (bf16*)carve((size_t)NN * 256 * 2);     // 25.6 MB
    bf16*   out1     = (bf16*)carve((size_t)NN * 256 * 2);     // 25.6 MB
    // layer-2 buffers alias h1 (dead after agg1)
    char*   l2base   = (char*)h1;
    bf16*   h2       = (bf16*)l2base;                          // 6.4 MB
    float*  a_src2   = (float*)(l2base + (size_t)NN * 64 * 2);
    float*  a_dst2   = a_src2 + NN;

    hipMemsetAsync(deg, 0, (size_t)NN * 4, stream);
    hipMemsetAsync(cursor, 0, (size_t)NN * 4, stream);

    detect_k<<<1, 256, 0, stream>>>((const unsigned int*)ei, flags);

    const int egrid = (TE + 255) / 256;
    count_deg_k<<<egrid, 256, 0, stream>>>(ei, flags, deg);
    scan_chunks_k<<<1, 256, 0, stream>>>(deg, chunkoff);
    scan_within_k<<<NCH, 256, 0, stream>>>(deg, chunkoff, offs);
    fill_csr_k<<<egrid, 256, 0, stream>>>(ei, flags, offs, cursor, csr_src);
    sort_csr_k<<<(NN + 63) / 64, 64, 0, stream>>>(offs, csr_src);

    gemm1_k<<<(NN + 31) / 32, 256, 0, stream>>>(x, W1, asr1, ads1, h1, a_src1, a_dst1);
    agg1_k<<<NN / 4, 256, 0, stream>>>(offs, csr_src, a_src1, a_dst1, h1, b1, out1);
    gemm2_k<<<(NN + 63) / 64, 256, 0, stream>>>(out1, W2, asr2, ads2, h2, a_src2, a_dst2);
    agg2_k<<<(NN + 3) / 4, 256, 0, stream>>>(offs, csr_src, a_src2, a_dst2, h2, b2, out);
}

// Round 9
// 432.960 us; speedup vs baseline: 1.2969x; 1.0558x over previous
//
#include <hip/hip_runtime.h>
#include <hip/hip_bf16.h>

// Problem constants (fixed by the reference)
#define NN 50000      // nodes
#define EE 800000     // raw edges
#define TE 850000     // edges + self loops
#define NCH 196       // ceil(NN/256) chunks for the scan

typedef __hip_bfloat16 bf16;

__device__ __forceinline__ float b2f(bf16 v) { return __bfloat162float(v); }
__device__ __forceinline__ float bu2f(unsigned short v) {
    return __uint_as_float((unsigned)v << 16);
}
__device__ __forceinline__ unsigned short f2bu(float v) {
    bf16 t = __float2bfloat16(v);
    return *(unsigned short*)&t;
}
__device__ __forceinline__ float lrelu(float e) { return (e > 0.f) ? e : 0.2f * e; }

// ---------------- runtime edge-index width detection ----------------
__global__ void detect_k(const unsigned int* __restrict__ eir, int* __restrict__ flags) {
    __shared__ int ci;
    int t = threadIdx.x;
    if (t == 0) ci = 0;
    __syncthreads();
    if (t < 64 && eir[2 * t + 1] == 0) atomicAdd(&ci, 1);
    __syncthreads();
    if (t == 0) flags[0] = (ci >= 32) ? 1 : 0;
}

__device__ __forceinline__ int clampn(int v) {
    return (v < 0) ? 0 : (v >= NN ? NN - 1 : v);
}

// ---------------- CSR build (by dst) ----------------
// 2 edges per thread, vectorized loads for both widths.

__global__ void count_deg_k(const void* __restrict__ ei, const int* __restrict__ flags,
                            int* __restrict__ deg) {
    int p = blockIdx.x * 256 + threadIdx.x;      // pair index
    int i0 = p * 2;
    if (i0 >= TE) return;
    int isi64 = flags[0];
    int d0, d1 = -1;
    if (i0 + 1 < EE) {
        if (isi64) {
            longlong2 v = ((const longlong2*)ei)[(EE >> 1) + p];
            d0 = clampn((int)v.x); d1 = clampn((int)v.y);
        } else {
            int2 v = ((const int2*)ei)[(EE >> 1) + p];
            d0 = clampn(v.x); d1 = clampn(v.y);
        }
    } else {
        d0 = (i0 < EE) ? clampn(isi64 ? (int)((const long long*)ei)[EE + i0]
                                      : ((const int*)ei)[EE + i0])
                       : (i0 - EE);
        if (i0 + 1 < TE)
            d1 = (i0 + 1 < EE) ? clampn(isi64 ? (int)((const long long*)ei)[EE + i0 + 1]
                                              : ((const int*)ei)[EE + i0 + 1])
                               : (i0 + 1 - EE);
    }
    atomicAdd(&deg[d0], 1);
    if (d1 >= 0) atomicAdd(&deg[d1], 1);
}

__global__ void scan_chunks_k(const int* __restrict__ deg, int* __restrict__ chunkoff) {
    __shared__ int s[256];
    int t = threadIdx.x;
    int sum = 0;
    if (t < NCH) {
        const int4* d4 = (const int4*)(deg + t * 256);
        int lim = (t == NCH - 1) ? (NN - t * 256) : 256;
        int i = 0;
        for (; i + 4 <= lim; i += 4) {
            int4 v = d4[i >> 2];
            sum += v.x + v.y + v.z + v.w;
        }
        for (; i < lim; ++i) sum += deg[t * 256 + i];
    }
    s[t] = sum;
    __syncthreads();
    for (int d = 1; d < 256; d <<= 1) {
        int v = (t >= d) ? s[t - d] : 0;
        __syncthreads();
        s[t] += v;
        __syncthreads();
    }
    if (t < NCH) chunkoff[t] = s[t] - sum;
}

__global__ void scan_within_k(const int* __restrict__ deg, const int* __restrict__ chunkoff,
                              int* __restrict__ offs) {
    __shared__ int s[256];
    int t = threadIdx.x, b = blockIdx.x, i = b * 256 + t;
    int v = (i < NN) ? deg[i] : 0;
    s[t] = v;
    __syncthreads();
    for (int d = 1; d < 256; d <<= 1) {
        int u = (t >= d) ? s[t - d] : 0;
        __syncthreads();
        s[t] += u;
        __syncthreads();
    }
    if (i < NN) offs[i] = chunkoff[b] + s[t] - v;
    if (i == NN - 1) offs[NN] = chunkoff[b] + s[t];
}

__global__ void fill_csr_k(const void* __restrict__ ei, const int* __restrict__ flags,
                           const int* __restrict__ offs,
                           int* __restrict__ cursor, int* __restrict__ csr_src) {
    int p = blockIdx.x * 256 + threadIdx.x;
    int i0 = p * 2;
    if (i0 >= TE) return;
    int isi64 = flags[0];
    int s0, d0, s1 = -1, d1 = -1;
    if (i0 + 1 < EE) {
        if (isi64) {
            longlong2 sv = ((const longlong2*)ei)[p];
            longlong2 dv = ((const longlong2*)ei)[(EE >> 1) + p];
            s0 = clampn((int)sv.x); s1 = clampn((int)sv.y);
            d0 = clampn((int)dv.x); d1 = clampn((int)dv.y);
        } else {
            int2 sv = ((const int2*)ei)[p];
            int2 dv = ((const int2*)ei)[(EE >> 1) + p];
            s0 = clampn(sv.x); s1 = clampn(sv.y);
            d0 = clampn(dv.x); d1 = clampn(dv.y);
        }
    } else {
        auto lde = [&](long long idx) {
            return clampn(isi64 ? (int)((const long long*)ei)[idx] : ((const int*)ei)[idx]);
        };
        if (i0 < EE) { s0 = lde(i0); d0 = lde((long long)EE + i0); }
        else         { s0 = i0 - EE; d0 = i0 - EE; }
        if (i0 + 1 < TE) {
            if (i0 + 1 < EE) { s1 = lde(i0 + 1); d1 = lde((long long)EE + i0 + 1); }
            else             { s1 = i0 + 1 - EE; d1 = i0 + 1 - EE; }
        }
    }
    int pos0 = offs[d0] + atomicAdd(&cursor[d0], 1);
    csr_src[pos0] = s0;
    if (d1 >= 0) {
        int pos1 = offs[d1] + atomicAdd(&cursor[d1], 1);
        csr_src[pos1] = s1;
    }
}

// Deterministic order: sort each dst bucket ascending (multiset -> unique array).
// LDS-staged insertion sort, transposed layout: 2-way bank aliasing = free.
#define SCAP 96
__global__ __launch_bounds__(64) void sort_csr_k(const int* __restrict__ offs,
                                                 int* __restrict__ csr_src) {
    __shared__ int buf[SCAP * 64];
    int t = threadIdx.x;
    int dst = blockIdx.x * 64 + t;
    if (dst >= NN) return;
    int s = offs[dst], e = offs[dst + 1];
    int d = e - s;
    if (d <= SCAP) {
        for (int i = 0; i < d; ++i) buf[i * 64 + t] = csr_src[s + i];
        for (int i = 1; i < d; ++i) {
            int v = buf[i * 64 + t];
            int j = i - 1;
            while (j >= 0 && buf[j * 64 + t] > v) {
                buf[(j + 1) * 64 + t] = buf[j * 64 + t]; --j;
            }
            buf[(j + 1) * 64 + t] = v;
        }
        for (int i = 0; i < d; ++i) csr_src[s + i] = buf[i * 64 + t];
    } else {
        for (int i = s + 1; i < e; ++i) {
            int v = csr_src[i];
            int j = i - 1;
            while (j >= s && csr_src[j] > v) { csr_src[j + 1] = csr_src[j]; --j; }
            csr_src[j + 1] = v;
        }
    }
}

// ---------------- Layer 1 GEMM: h1 = x@W1 (bf16 out) + alpha partials -------
__global__ __launch_bounds__(256) void gemm1_k(
    const float* __restrict__ x, const float* __restrict__ W1,
    const float* __restrict__ asr, const float* __restrict__ ads,
    bf16* __restrict__ h1, float* __restrict__ a_src, float* __restrict__ a_dst) {
    __shared__ float4 xs4[32 * 32];
    int tid = threadIdx.x;
    int base = blockIdx.x * 32;
    const float4* x4 = (const float4*)x;
    for (int i = tid; i < 1024; i += 256) {
        int row = base + (i >> 5);
        xs4[i] = (row < NN) ? x4[(size_t)base * 32 + i] : make_float4(0.f, 0.f, 0.f, 0.f);
    }
    __syncthreads();
    int cg = tid & 63, rg = tid >> 6;
    int c0 = cg * 4;
    float4 acc[8];
#pragma unroll
    for (int r = 0; r < 8; ++r) acc[r] = make_float4(0.f, 0.f, 0.f, 0.f);
    for (int kq = 0; kq < 32; ++kq) {
        float4 w0 = *(const float4*)&W1[(kq * 4 + 0) * 256 + c0];
        float4 w1 = *(const float4*)&W1[(kq * 4 + 1) * 256 + c0];
        float4 w2 = *(const float4*)&W1[(kq * 4 + 2) * 256 + c0];
        float4 w3 = *(const float4*)&W1[(kq * 4 + 3) * 256 + c0];
#pragma unroll
        for (int r = 0; r < 8; ++r) {
            float4 xv = xs4[(rg * 8 + r) * 32 + kq];
            acc[r].x += xv.x * w0.x + xv.y * w1.x + xv.z * w2.x + xv.w * w3.x;
            acc[r].y += xv.x * w0.y + xv.y * w1.y + xv.z * w2.y + xv.w * w3.y;
            acc[r].z += xv.x * w0.z + xv.y * w1.z + xv.z * w2.z + xv.w * w3.z;
            acc[r].w += xv.x * w0.w + xv.y * w1.w + xv.z * w2.w + xv.w * w3.w;
        }
    }
    int h = cg >> 2;
    float sa0 = asr[c0], sa1 = asr[c0 + 1], sa2 = asr[c0 + 2], sa3 = asr[c0 + 3];
    float da0 = ads[c0], da1 = ads[c0 + 1], da2 = ads[c0 + 2], da3 = ads[c0 + 3];
#pragma unroll
    for (int r = 0; r < 8; ++r) {
        int row = base + rg * 8 + r;
        if (row < NN) {
            ushort4 st;
            st.x = f2bu(acc[r].x); st.y = f2bu(acc[r].y);
            st.z = f2bu(acc[r].z); st.w = f2bu(acc[r].w);
            *(ushort4*)&h1[(size_t)row * 256 + c0] = st;
            float ps = acc[r].x * sa0 + acc[r].y * sa1 + acc[r].z * sa2 + acc[r].w * sa3;
            float pd = acc[r].x * da0 + acc[r].y * da1 + acc[r].z * da2 + acc[r].w * da3;
            ps += __shfl_xor(ps, 1, 64); ps += __shfl_xor(ps, 2, 64);
            pd += __shfl_xor(pd, 1, 64); pd += __shfl_xor(pd, 2, 64);
            if ((cg & 3) == 0) {
                a_src[row * 16 + h] = ps;
                a_dst[row * 16 + h] = pd;
            }
        }
    }
}

// ---------------- Layer 1 aggregation: wave-per-dst, 8-edge tiles -----------
// Wave = one dst. Lane owns channels 4*lane..4*lane+3 (consumer head hc=lane>>2).
// Weight role: lane = (we = lane>>4 in 0..3, wh = lane&15); two weight regs
// cover 8 edges/tile -> 8 independent gathers in flight. Raw-exp softmax.
__global__ __launch_bounds__(256) void agg1_k(
    const int* __restrict__ offs, const int* __restrict__ csr_src,
    const float* __restrict__ a_src, const float* __restrict__ a_dst,
    const bf16* __restrict__ h1, const float* __restrict__ b1,
    bf16* __restrict__ out1) {
    int wv = threadIdx.x >> 6, lane = threadIdx.x & 63;
    int dst = blockIdx.x * 4 + wv;          // grid = NN/4 exactly
    int start = offs[dst], end = offs[dst + 1];
    int we = lane >> 4, wh = lane & 15;
    int hc = lane >> 2;
    float adst_w = a_dst[dst * 16 + wh];
    float ax = 0.f, ay = 0.f, az = 0.f, aw = 0.f;
    float dsum = 0.f;
    int t0 = start;
    for (; t0 + 8 <= end; t0 += 8) {
        int sra = csr_src[t0 + we];
        int srb = csr_src[t0 + 4 + we];
        float wa = __expf(lrelu(a_src[sra * 16 + wh] + adst_w));
        float wb = __expf(lrelu(a_src[srb * 16 + wh] + adst_w));
        dsum += wa + wb;
#pragma unroll
        for (int j = 0; j < 4; ++j) {
            int sl = j * 16 + hc;
            float wja = __shfl(wa, sl, 64);
            int sja = __shfl(sra, sl, 64);
            float wjb = __shfl(wb, sl, 64);
            int sjb = __shfl(srb, sl, 64);
            ushort4 ha = *(const ushort4*)&h1[(size_t)sja * 256 + lane * 4];
            ushort4 hb = *(const ushort4*)&h1[(size_t)sjb * 256 + lane * 4];
            ax += wja * bu2f(ha.x) + wjb * bu2f(hb.x);
            ay += wja * bu2f(ha.y) + wjb * bu2f(hb.y);
            az += wja * bu2f(ha.z) + wjb * bu2f(hb.z);
            aw += wja * bu2f(ha.w) + wjb * bu2f(hb.w);
        }
    }
    if (t0 < end) {
        int n = end - t0;
        float wa = 0.f, wb = 0.f; int sra = 0, srb = 0;
        if (we < n) {
            sra = csr_src[t0 + we];
            wa = __expf(lrelu(a_src[sra * 16 + wh] + adst_w));
        }
        if (we + 4 < n) {
            srb = csr_src[t0 + 4 + we];
            wb = __expf(lrelu(a_src[srb * 16 + wh] + adst_w));
        }
        dsum += wa + wb;
        int na = (n < 4) ? n : 4;
        for (int j = 0; j < na; ++j) {
            int sl = j * 16 + hc;
            float wj = __shfl(wa, sl, 64);
            int sj = __shfl(sra, sl, 64);
            ushort4 hv = *(const ushort4*)&h1[(size_t)sj * 256 + lane * 4];
            ax += wj * bu2f(hv.x); ay += wj * bu2f(hv.y);
            az += wj * bu2f(hv.z); aw += wj * bu2f(hv.w);
        }
        for (int j = 0; j + 4 < n; ++j) {
            int sl = j * 16 + hc;
            float wj = __shfl(wb, sl, 64);
            int sj = __shfl(srb, sl, 64);
            ushort4 hv = *(const ushort4*)&h1[(size_t)sj * 256 + lane * 4];
            ax += wj * bu2f(hv.x); ay += wj * bu2f(hv.y);
            az += wj * bu2f(hv.z); aw += wj * bu2f(hv.w);
        }
    }
    dsum += __shfl_xor(dsum, 16, 64);
    dsum += __shfl_xor(dsum, 32, 64);
    float invd = 1.f / (__shfl(dsum, hc, 64) + 1e-16f);
    float4 bv = *(const float4*)&b1[lane * 4];
    ushort4 st;
    st.x = f2bu(ax * invd + bv.x);
    st.y = f2bu(ay * invd + bv.y);
    st.z = f2bu(az * invd + bv.z);
    st.w = f2bu(aw * invd + bv.w);
    *(ushort4*)&out1[(size_t)dst * 256 + lane * 4] = st;
}

// ---------------- Layer 2 GEMM: h2 = out1@W2 (bf16 out) + alpha2 ------------
__global__ __launch_bounds__(256) void gemm2_k(
    const bf16* __restrict__ out1, const float* __restrict__ W2,
    const float* __restrict__ asr2, const float* __restrict__ ads2,
    bf16* __restrict__ h2, float* __restrict__ a_src2, float* __restrict__ a_dst2) {
    __shared__ bf16 ys[64 * 256];   // 32 KB
    int tid = threadIdx.x;
    int base = blockIdx.x * 64;
    uint4* ys16 = (uint4*)ys;
    const uint4* in16 = (const uint4*)out1;
    for (int i = tid; i < 2048; i += 256) {
        int row = base + (i >> 5);
        uint4 z; z.x = z.y = z.z = z.w = 0u;
        ys16[i] = (row < NN) ? in16[(size_t)base * 32 + i] : z;
    }
    __syncthreads();
    int cg = tid & 31, rg = tid >> 5;
    int c0 = cg * 2;
    float2 acc[8];
#pragma unroll
    for (int r = 0; r < 8; ++r) acc[r] = make_float2(0.f, 0.f);
    for (int kq = 0; kq < 64; ++kq) {
        float2 w0 = *(const float2*)&W2[(kq * 4 + 0) * 64 + c0];
        float2 w1 = *(const float2*)&W2[(kq * 4 + 1) * 64 + c0];
        float2 w2 = *(const float2*)&W2[(kq * 4 + 2) * 64 + c0];
        float2 w3 = *(const float2*)&W2[(kq * 4 + 3) * 64 + c0];
#pragma unroll
        for (int r = 0; r < 8; ++r) {
            const __hip_bfloat162* yp =
                (const __hip_bfloat162*)&ys[(rg * 8 + r) * 256 + kq * 4];
            float2 y01 = __bfloat1622float2(yp[0]);
            float2 y23 = __bfloat1622float2(yp[1]);
            acc[r].x += y01.x * w0.x + y01.y * w1.x + y23.x * w2.x + y23.y * w3.x;
            acc[r].y += y01.x * w0.y + y01.y * w1.y + y23.x * w2.y + y23.y * w3.y;
        }
    }
    float sa0 = asr2[c0], sa1 = asr2[c0 + 1];
    float da0 = ads2[c0], da1 = ads2[c0 + 1];
#pragma unroll
    for (int r = 0; r < 8; ++r) {
        int row = base + rg * 8 + r;
        if (row < NN) {
            __hip_bfloat162 hb;
            hb.x = __float2bfloat16(acc[r].x);
            hb.y = __float2bfloat16(acc[r].y);
            *(__hip_bfloat162*)&h2[(size_t)row * 64 + c0] = hb;
            float ps = acc[r].x * sa0 + acc[r].y * sa1;
            float pd = acc[r].x * da0 + acc[r].y * da1;
#pragma unroll
            for (int o = 1; o <= 16; o <<= 1) {
                ps += __shfl_xor(ps, o, 64);
                pd += __shfl_xor(pd, o, 64);
            }
            if (cg == 0) { a_src2[row] = ps; a_dst2[row] = pd; }
        }
    }
}

// ---------------- Layer 2 aggregation + sigmoid (f32 out) -------------------
// block 256 = 4 dst (one wave each); lane = channel. 4-unrolled consumer.
__global__ __launch_bounds__(256) void agg2_k(
    const int* __restrict__ offs, const int* __restrict__ csr_src,
    const float* __restrict__ a_src2, const float* __restrict__ a_dst2,
    const bf16* __restrict__ h2, const float* __restrict__ b2,
    float* __restrict__ out) {
    int wv = threadIdx.x >> 6;
    int lane = threadIdx.x & 63;
    int dst = blockIdx.x * 4 + wv;
    if (dst >= NN) return;
    int start = offs[dst], end = offs[dst + 1];
    float adst = a_dst2[dst];
    float acc = 0.f, dsum = 0.f;
    for (int t0 = start; t0 < end; t0 += 64) {
        int n = end - t0; if (n > 64) n = 64;
        float wr = 0.f; int sr = 0;
        if (lane < n) {
            sr = csr_src[t0 + lane];
            wr = __expf(lrelu(a_src2[sr] + adst));
        }
        dsum += wr;
        int j = 0;
        for (; j + 4 <= n; j += 4) {
            float w0 = __shfl(wr, j, 64),     w1 = __shfl(wr, j + 1, 64);
            float w2 = __shfl(wr, j + 2, 64), w3 = __shfl(wr, j + 3, 64);
            int s0 = __shfl(sr, j, 64),       s1 = __shfl(sr, j + 1, 64);
            int s2 = __shfl(sr, j + 2, 64),   s3 = __shfl(sr, j + 3, 64);
            float h0 = b2f(h2[(size_t)s0 * 64 + lane]);
            float h1v = b2f(h2[(size_t)s1 * 64 + lane]);
            float h2v = b2f(h2[(size_t)s2 * 64 + lane]);
            float h3 = b2f(h2[(size_t)s3 * 64 + lane]);
            acc += w0 * h0 + w1 * h1v + w2 * h2v + w3 * h3;
        }
        for (; j < n; ++j) {
            float wj = __shfl(wr, j, 64);
            int sj = __shfl(sr, j, 64);
            acc += wj * b2f(h2[(size_t)sj * 64 + lane]);
        }
    }
#pragma unroll
    for (int o = 32; o >= 1; o >>= 1) dsum += __shfl_xor(dsum, o, 64);
    float o = acc / (dsum + 1e-16f) + b2[lane];
    out[(size_t)dst * 64 + lane] = 1.f / (1.f + __expf(-o));
}

// ---------------- host ------------------------------------------------------

extern "C" void kernel_launch(void* const* d_in, const int* in_sizes, int n_in,
                              void* d_out, int out_size, void* d_ws, size_t ws_size,
                              hipStream_t stream) {
    const float* x    = (const float*)d_in[0];
    const void*  ei   = d_in[1];
    const float* W1   = (const float*)d_in[2];
    const float* asr1 = (const float*)d_in[3];
    const float* ads1 = (const float*)d_in[4];
    const float* b1   = (const float*)d_in[5];
    const float* W2   = (const float*)d_in[6];
    const float* asr2 = (const float*)d_in[7];
    const float* ads2 = (const float*)d_in[8];
    const float* b2   = (const float*)d_in[9];
    float* out = (float*)d_out;

    char* w = (char*)d_ws;
    auto carve = [&](size_t bytes) {
        void* p = (void*)w;
        w += (bytes + 255) & ~(size_t)255;
        return p;
    };
    int*    flags    = (int*)carve(256);
    int*    csr_src  = (int*)carve((size_t)TE * 4);
    int*    offs     = (int*)carve((size_t)(NN + 1) * 4);
    int*    deg      = (int*)carve((size_t)NN * 4);
    int*    cursor   = (int*)carve((size_t)NN * 4);
    int*    chunkoff = (int*)carve(256 * 4);
    float*  a_src1   = (float*)carve((size_t)NN * 16 * 4);
    float*  a_dst1   = (float*)carve((size_t)NN * 16 * 4);
    bf16*   h1       = (bf16*)carve((size_t)NN * 256 * 2);
    bf16*   out1     = (bf16*)carve((size_t)NN * 256 * 2);
    // layer-2 buffers alias h1 (dead after agg1)
    char*   l2base   = (char*)h1;
    bf16*   h2       = (bf16*)l2base;
    float*  a_src2   = (float*)(l2base + (size_t)NN * 64 * 2);
    float*  a_dst2   = a_src2 + NN;

    hipMemsetAsync(deg, 0, (size_t)NN * 4, stream);
    hipMemsetAsync(cursor, 0, (size_t)NN * 4, stream);

    detect_k<<<1, 256, 0, stream>>>((const unsigned int*)ei, flags);

    const int pgrid = ((TE + 1) / 2 + 255) / 256;
    count_deg_k<<<pgrid, 256, 0, stream>>>(ei, flags, deg);
    scan_chunks_k<<<1, 256, 0, stream>>>(deg, chunkoff);
    scan_within_k<<<NCH, 256, 0, stream>>>(deg, chunkoff, offs);
    fill_csr_k<<<pgrid, 256, 0, stream>>>(ei, flags, offs, cursor, csr_src);
    sort_csr_k<<<(NN + 63) / 64, 64, 0, stream>>>(offs, csr_src);

    gemm1_k<<<(NN + 31) / 32, 256, 0, stream>>>(x, W1, asr1, ads1, h1, a_src1, a_dst1);
    agg1_k<<<NN / 4, 256, 0, stream>>>(offs, csr_src, a_src1, a_dst1, h1, b1, out1);
    gemm2_k<<<(NN + 63) / 64, 256, 0, stream>>>(out1, W2, asr2, ads2, h2, a_src2, a_dst2);
    agg2_k<<<(NN + 3) / 4, 256, 0, stream>>>(offs, csr_src, a_src2, a_dst2, h2, b2, out);
}

// Round 10
// 408.298 us; speedup vs baseline: 1.3752x; 1.0604x over previous
//
#include <hip/hip_runtime.h>
#include <hip/hip_bf16.h>

// Problem constants (fixed by the reference)
#define NN 50000      // nodes
#define EE 800000     // raw edges
#define TE 850000     // edges + self loops
#define NCH 196       // ceil(NN/256) chunks for the scan

typedef __hip_bfloat16 bf16;

__device__ __forceinline__ float b2f(bf16 v) { return __bfloat162float(v); }
__device__ __forceinline__ float bu2f(unsigned short v) {
    return __uint_as_float((unsigned)v << 16);
}
__device__ __forceinline__ unsigned short f2bu(float v) {
    bf16 t = __float2bfloat16(v);
    return *(unsigned short*)&t;
}
__device__ __forceinline__ float lrelu(float e) { return (e > 0.f) ? e : 0.2f * e; }
__device__ __forceinline__ int clampn(int v) {
    return (v < 0) ? 0 : (v >= NN ? NN - 1 : v);
}

// Per-block int64 detection: first 64 odd words of edge_index are all zero iff
// the tensor is int64 (high words of small positives). L1-hot after block 0.
__device__ __forceinline__ int block_isi64(const void* ei) {
    __shared__ int sflag;
    int t = threadIdx.x;
    if (t < 64) {
        unsigned z = (((const unsigned*)ei)[2 * t + 1] == 0u) ? 1u : 0u;
        unsigned long long m = __ballot(z);
        if (t == 0) sflag = (__popcll(m) >= 32) ? 1 : 0;
    }
    __syncthreads();
    return sflag;
}

// ---------------- CSR build (by dst), 2 edges/thread ----------------

__global__ void count_deg_k(const void* __restrict__ ei, int* __restrict__ deg) {
    int isi64 = block_isi64(ei);
    int p = blockIdx.x * 256 + threadIdx.x;      // pair index
    int i0 = p * 2;
    if (i0 >= TE) return;
    int d0, d1 = -1;
    if (i0 + 1 < EE) {
        if (isi64) {
            longlong2 v = ((const longlong2*)ei)[(EE >> 1) + p];
            d0 = clampn((int)v.x); d1 = clampn((int)v.y);
        } else {
            int2 v = ((const int2*)ei)[(EE >> 1) + p];
            d0 = clampn(v.x); d1 = clampn(v.y);
        }
    } else {
        d0 = (i0 < EE) ? clampn(isi64 ? (int)((const long long*)ei)[EE + i0]
                                      : ((const int*)ei)[EE + i0])
                       : (i0 - EE);
        if (i0 + 1 < TE)
            d1 = (i0 + 1 < EE) ? clampn(isi64 ? (int)((const long long*)ei)[EE + i0 + 1]
                                              : ((const int*)ei)[EE + i0 + 1])
                               : (i0 + 1 - EE);
    }
    atomicAdd(&deg[d0], 1);
    if (d1 >= 0) atomicAdd(&deg[d1], 1);
}

__global__ void scan_chunks_k(const int* __restrict__ deg, int* __restrict__ chunkoff) {
    __shared__ int s[256];
    int t = threadIdx.x;
    int sum = 0;
    if (t < NCH) {
        const int4* d4 = (const int4*)(deg + t * 256);
        int lim = (t == NCH - 1) ? (NN - t * 256) : 256;
        int i = 0;
        for (; i + 4 <= lim; i += 4) {
            int4 v = d4[i >> 2];
            sum += v.x + v.y + v.z + v.w;
        }
        for (; i < lim; ++i) sum += deg[t * 256 + i];
    }
    s[t] = sum;
    __syncthreads();
    for (int d = 1; d < 256; d <<= 1) {
        int v = (t >= d) ? s[t - d] : 0;
        __syncthreads();
        s[t] += v;
        __syncthreads();
    }
    if (t < NCH) chunkoff[t] = s[t] - sum;
}

__global__ void scan_within_k(const int* __restrict__ deg, const int* __restrict__ chunkoff,
                              int* __restrict__ offs) {
    __shared__ int s[256];
    int t = threadIdx.x, b = blockIdx.x, i = b * 256 + t;
    int v = (i < NN) ? deg[i] : 0;
    s[t] = v;
    __syncthreads();
    for (int d = 1; d < 256; d <<= 1) {
        int u = (t >= d) ? s[t - d] : 0;
        __syncthreads();
        s[t] += u;
        __syncthreads();
    }
    if (i < NN) offs[i] = chunkoff[b] + s[t] - v;
    if (i == NN - 1) offs[NN] = chunkoff[b] + s[t];
}

// Reverse-fill: slot = offs[d] + (--deg[d]); deg consumed (scans already done).
__global__ void fill_csr_k(const void* __restrict__ ei, const int* __restrict__ offs,
                           int* __restrict__ deg, int* __restrict__ csr_src) {
    int isi64 = block_isi64(ei);
    int p = blockIdx.x * 256 + threadIdx.x;
    int i0 = p * 2;
    if (i0 >= TE) return;
    int s0, d0, s1 = -1, d1 = -1;
    if (i0 + 1 < EE) {
        if (isi64) {
            longlong2 sv = ((const longlong2*)ei)[p];
            longlong2 dv = ((const longlong2*)ei)[(EE >> 1) + p];
            s0 = clampn((int)sv.x); s1 = clampn((int)sv.y);
            d0 = clampn((int)dv.x); d1 = clampn((int)dv.y);
        } else {
            int2 sv = ((const int2*)ei)[p];
            int2 dv = ((const int2*)ei)[(EE >> 1) + p];
            s0 = clampn(sv.x); s1 = clampn(sv.y);
            d0 = clampn(dv.x); d1 = clampn(dv.y);
        }
    } else {
        auto lde = [&](long long idx) {
            return clampn(isi64 ? (int)((const long long*)ei)[idx] : ((const int*)ei)[idx]);
        };
        if (i0 < EE) { s0 = lde(i0); d0 = lde((long long)EE + i0); }
        else         { s0 = i0 - EE; d0 = i0 - EE; }
        if (i0 + 1 < TE) {
            if (i0 + 1 < EE) { s1 = lde(i0 + 1); d1 = lde((long long)EE + i0 + 1); }
            else             { s1 = i0 + 1 - EE; d1 = i0 + 1 - EE; }
        }
    }
    int pos0 = offs[d0] + atomicSub(&deg[d0], 1) - 1;
    csr_src[pos0] = s0;
    if (d1 >= 0) {
        int pos1 = offs[d1] + atomicSub(&deg[d1], 1) - 1;
        csr_src[pos1] = s1;
    }
}

// Canonicalize bucket order: wave per dst computes each element's rank in the
// ascending order (ties broken arbitrarily among identical values -> output
// CONTENT is the sorted multiset = deterministic regardless of atomic order).
__global__ __launch_bounds__(256) void rank_csr_k(const int* __restrict__ offs,
                                                  const int* __restrict__ csr_in,
                                                  int* __restrict__ csr_out) {
    int wv = threadIdx.x >> 6, lane = threadIdx.x & 63;
    int dst = blockIdx.x * 4 + wv;
    if (dst >= NN) return;
    int s = offs[dst], e = offs[dst + 1];
    int d = e - s;
    if (d <= 64) {
        int v = (lane < d) ? csr_in[s + lane] : 0x7fffffff;
        int rank = 0;
        for (int j = 0; j < d; ++j) {
            int vj = __shfl(v, j, 64);
            rank += (vj < v || (vj == v && j < lane)) ? 1 : 0;
        }
        if (lane < d) csr_out[s + rank] = v;
    } else {                       // defensive; degrees here are ~<=50
        for (int i = lane; i < d; i += 64) {
            int v = csr_in[s + i];
            int rank = 0;
            for (int j = 0; j < d; ++j) {
                int vj = csr_in[s + j];
                rank += (vj < v || (vj == v && j < i)) ? 1 : 0;
            }
            csr_out[s + rank] = v;
        }
    }
}

// ---------------- Layer 1 GEMM: h1 = x@W1 (bf16 out) + alpha partials -------
// block = 32 rows x 256 cols; thread = 4 rows (rg*4) x 8 cols (cg*8).
// 4 ds_read_b128 per kq per thread (half of the 8-row x 4-col mapping).
__global__ __launch_bounds__(256) void gemm1_k(
    const float* __restrict__ x, const float* __restrict__ W1,
    const float* __restrict__ asr, const float* __restrict__ ads,
    bf16* __restrict__ h1, float* __restrict__ a_src, float* __restrict__ a_dst) {
    __shared__ float4 xs4[32 * 32];
    int tid = threadIdx.x;
    int base = blockIdx.x * 32;
    const float4* x4 = (const float4*)x;
    for (int i = tid; i < 1024; i += 256) {
        int row = base + (i >> 5);
        xs4[i] = (row < NN) ? x4[(size_t)base * 32 + i] : make_float4(0.f, 0.f, 0.f, 0.f);
    }
    __syncthreads();
    int cg = tid & 31, rg = tid >> 5;
    int c0 = cg * 8, r0 = rg * 4;
    float acc[4][8];
#pragma unroll
    for (int r = 0; r < 4; ++r)
#pragma unroll
        for (int c = 0; c < 8; ++c) acc[r][c] = 0.f;
    for (int kq = 0; kq < 32; ++kq) {
        float4 wv[4][2];
#pragma unroll
        for (int k = 0; k < 4; ++k) {
            wv[k][0] = *(const float4*)&W1[(kq * 4 + k) * 256 + c0];
            wv[k][1] = *(const float4*)&W1[(kq * 4 + k) * 256 + c0 + 4];
        }
#pragma unroll
        for (int r = 0; r < 4; ++r) {
            float4 xv = xs4[(r0 + r) * 32 + kq];
            float xk[4] = {xv.x, xv.y, xv.z, xv.w};
#pragma unroll
            for (int k = 0; k < 4; ++k) {
                acc[r][0] += xk[k] * wv[k][0].x;
                acc[r][1] += xk[k] * wv[k][0].y;
                acc[r][2] += xk[k] * wv[k][0].z;
                acc[r][3] += xk[k] * wv[k][0].w;
                acc[r][4] += xk[k] * wv[k][1].x;
                acc[r][5] += xk[k] * wv[k][1].y;
                acc[r][6] += xk[k] * wv[k][1].z;
                acc[r][7] += xk[k] * wv[k][1].w;
            }
        }
    }
    int h = cg >> 1;
    float sa[8], da[8];
#pragma unroll
    for (int c = 0; c < 8; ++c) { sa[c] = asr[c0 + c]; da[c] = ads[c0 + c]; }
#pragma unroll
    for (int r = 0; r < 4; ++r) {
        int row = base + r0 + r;
        if (row < NN) {
            uint4 st;
            st.x = (unsigned)f2bu(acc[r][0]) | ((unsigned)f2bu(acc[r][1]) << 16);
            st.y = (unsigned)f2bu(acc[r][2]) | ((unsigned)f2bu(acc[r][3]) << 16);
            st.z = (unsigned)f2bu(acc[r][4]) | ((unsigned)f2bu(acc[r][5]) << 16);
            st.w = (unsigned)f2bu(acc[r][6]) | ((unsigned)f2bu(acc[r][7]) << 16);
            *(uint4*)&h1[(size_t)row * 256 + c0] = st;
            float ps = 0.f, pd = 0.f;
#pragma unroll
            for (int c = 0; c < 8; ++c) { ps += acc[r][c] * sa[c]; pd += acc[r][c] * da[c]; }
            ps += __shfl_xor(ps, 1, 64);
            pd += __shfl_xor(pd, 1, 64);
            if ((cg & 1) == 0) {
                a_src[row * 16 + h] = ps;
                a_dst[row * 16 + h] = pd;
            }
        }
    }
}

// ---------------- Layer 1 aggregation: wave-per-dst, 4-edge tiles -----------
// (round-8 form: fastest measured; 8-edge tiles were neutral w/ higher VGPR)
__global__ __launch_bounds__(256) void agg1_k(
    const int* __restrict__ offs, const int* __restrict__ csr_src,
    const float* __restrict__ a_src, const float* __restrict__ a_dst,
    const bf16* __restrict__ h1, const float* __restrict__ b1,
    bf16* __restrict__ out1) {
    int wv = threadIdx.x >> 6, lane = threadIdx.x & 63;
    int dst = blockIdx.x * 4 + wv;          // grid = NN/4 exactly
    int start = offs[dst], end = offs[dst + 1];
    int we = lane >> 4, wh = lane & 15;     // weight role
    int hc = lane >> 2;                      // consumer head
    float adst_w = a_dst[dst * 16 + wh];
    float ax = 0.f, ay = 0.f, az = 0.f, aw = 0.f;
    float dsum = 0.f;
    int t0 = start;
    for (; t0 + 4 <= end; t0 += 4) {
        int sr = csr_src[t0 + we];
        float wr = __expf(lrelu(a_src[sr * 16 + wh] + adst_w));
        dsum += wr;
#pragma unroll
        for (int j = 0; j < 4; ++j) {
            int sl = j * 16 + hc;
            float wj = __shfl(wr, sl, 64);
            int sj = __shfl(sr, sl, 64);
            ushort4 hv = *(const ushort4*)&h1[(size_t)sj * 256 + lane * 4];
            ax += wj * bu2f(hv.x);
            ay += wj * bu2f(hv.y);
            az += wj * bu2f(hv.z);
            aw += wj * bu2f(hv.w);
        }
    }
    if (t0 < end) {
        int n = end - t0;
        float wr = 0.f; int sr = 0;
        if (we < n) {
            sr = csr_src[t0 + we];
            wr = __expf(lrelu(a_src[sr * 16 + wh] + adst_w));
        }
        dsum += wr;
        for (int j = 0; j < n; ++j) {
            int sl = j * 16 + hc;
            float wj = __shfl(wr, sl, 64);
            int sj = __shfl(sr, sl, 64);
            ushort4 hv = *(const ushort4*)&h1[(size_t)sj * 256 + lane * 4];
            ax += wj * bu2f(hv.x);
            ay += wj * bu2f(hv.y);
            az += wj * bu2f(hv.z);
            aw += wj * bu2f(hv.w);
        }
    }
    dsum += __shfl_xor(dsum, 16, 64);
    dsum += __shfl_xor(dsum, 32, 64);
    float invd = 1.f / (__shfl(dsum, hc, 64) + 1e-16f);
    float4 bv = *(const float4*)&b1[lane * 4];
    ushort4 st;
    st.x = f2bu(ax * invd + bv.x);
    st.y = f2bu(ay * invd + bv.y);
    st.z = f2bu(az * invd + bv.z);
    st.w = f2bu(aw * invd + bv.w);
    *(ushort4*)&out1[(size_t)dst * 256 + lane * 4] = st;
}

// ---------------- Layer 2 GEMM: h2 = out1@W2 (bf16 out) + alpha2 ------------
__global__ __launch_bounds__(256) void gemm2_k(
    const bf16* __restrict__ out1, const float* __restrict__ W2,
    const float* __restrict__ asr2, const float* __restrict__ ads2,
    bf16* __restrict__ h2, float* __restrict__ a_src2, float* __restrict__ a_dst2) {
    __shared__ bf16 ys[64 * 256];   // 32 KB
    int tid = threadIdx.x;
    int base = blockIdx.x * 64;
    uint4* ys16 = (uint4*)ys;
    const uint4* in16 = (const uint4*)out1;
    for (int i = tid; i < 2048; i += 256) {
        int row = base + (i >> 5);
        uint4 z; z.x = z.y = z.z = z.w = 0u;
        ys16[i] = (row < NN) ? in16[(size_t)base * 32 + i] : z;
    }
    __syncthreads();
    int cg = tid & 31, rg = tid >> 5;
    int c0 = cg * 2;
    float2 acc[8];
#pragma unroll
    for (int r = 0; r < 8; ++r) acc[r] = make_float2(0.f, 0.f);
    for (int kq = 0; kq < 64; ++kq) {
        float2 w0 = *(const float2*)&W2[(kq * 4 + 0) * 64 + c0];
        float2 w1 = *(const float2*)&W2[(kq * 4 + 1) * 64 + c0];
        float2 w2 = *(const float2*)&W2[(kq * 4 + 2) * 64 + c0];
        float2 w3 = *(const float2*)&W2[(kq * 4 + 3) * 64 + c0];
#pragma unroll
        for (int r = 0; r < 8; ++r) {
            const __hip_bfloat162* yp =
                (const __hip_bfloat162*)&ys[(rg * 8 + r) * 256 + kq * 4];
            float2 y01 = __bfloat1622float2(yp[0]);
            float2 y23 = __bfloat1622float2(yp[1]);
            acc[r].x += y01.x * w0.x + y01.y * w1.x + y23.x * w2.x + y23.y * w3.x;
            acc[r].y += y01.x * w0.y + y01.y * w1.y + y23.x * w2.y + y23.y * w3.y;
        }
    }
    float sa0 = asr2[c0], sa1 = asr2[c0 + 1];
    float da0 = ads2[c0], da1 = ads2[c0 + 1];
#pragma unroll
    for (int r = 0; r < 8; ++r) {
        int row = base + rg * 8 + r;
        if (row < NN) {
            __hip_bfloat162 hb;
            hb.x = __float2bfloat16(acc[r].x);
            hb.y = __float2bfloat16(acc[r].y);
            *(__hip_bfloat162*)&h2[(size_t)row * 64 + c0] = hb;
            float ps = acc[r].x * sa0 + acc[r].y * sa1;
            float pd = acc[r].x * da0 + acc[r].y * da1;
#pragma unroll
            for (int o = 1; o <= 16; o <<= 1) {
                ps += __shfl_xor(ps, o, 64);
                pd += __shfl_xor(pd, o, 64);
            }
            if (cg == 0) { a_src2[row] = ps; a_dst2[row] = pd; }
        }
    }
}

// ---------------- Layer 2 aggregation + sigmoid (f32 out) -------------------
__global__ __launch_bounds__(256) void agg2_k(
    const int* __restrict__ offs, const int* __restrict__ csr_src,
    const float* __restrict__ a_src2, const float* __restrict__ a_dst2,
    const bf16* __restrict__ h2, const float* __restrict__ b2,
    float* __restrict__ out) {
    int wv = threadIdx.x >> 6;
    int lane = threadIdx.x & 63;
    int dst = blockIdx.x * 4 + wv;
    if (dst >= NN) return;
    int start = offs[dst], end = offs[dst + 1];
    float adst = a_dst2[dst];
    float acc = 0.f, dsum = 0.f;
    for (int t0 = start; t0 < end; t0 += 64) {
        int n = end - t0; if (n > 64) n = 64;
        float wr = 0.f; int sr = 0;
        if (lane < n) {
            sr = csr_src[t0 + lane];
            wr = __expf(lrelu(a_src2[sr] + adst));
        }
        dsum += wr;
        int j = 0;
        for (; j + 4 <= n; j += 4) {
            float w0 = __shfl(wr, j, 64),     w1 = __shfl(wr, j + 1, 64);
            float w2 = __shfl(wr, j + 2, 64), w3 = __shfl(wr, j + 3, 64);
            int s0 = __shfl(sr, j, 64),       s1 = __shfl(sr, j + 1, 64);
            int s2 = __shfl(sr, j + 2, 64),   s3 = __shfl(sr, j + 3, 64);
            float h0 = b2f(h2[(size_t)s0 * 64 + lane]);
            float h1v = b2f(h2[(size_t)s1 * 64 + lane]);
            float h2v = b2f(h2[(size_t)s2 * 64 + lane]);
            float h3 = b2f(h2[(size_t)s3 * 64 + lane]);
            acc += w0 * h0 + w1 * h1v + w2 * h2v + w3 * h3;
        }
        for (; j < n; ++j) {
            float wj = __shfl(wr, j, 64);
            int sj = __shfl(sr, j, 64);
            acc += wj * b2f(h2[(size_t)sj * 64 + lane]);
        }
    }
#pragma unroll
    for (int o = 32; o >= 1; o >>= 1) dsum += __shfl_xor(dsum, o, 64);
    float o = acc / (dsum + 1e-16f) + b2[lane];
    out[(size_t)dst * 64 + lane] = 1.f / (1.f + __expf(-o));
}

// ---------------- host ------------------------------------------------------

extern "C" void kernel_launch(void* const* d_in, const int* in_sizes, int n_in,
                              void* d_out, int out_size, void* d_ws, size_t ws_size,
                              hipStream_t stream) {
    const float* x    = (const float*)d_in[0];
    const void*  ei   = d_in[1];
    const float* W1   = (const float*)d_in[2];
    const float* asr1 = (const float*)d_in[3];
    const float* ads1 = (const float*)d_in[4];
    const float* b1   = (const float*)d_in[5];
    const float* W2   = (const float*)d_in[6];
    const float* asr2 = (const float*)d_in[7];
    const float* ads2 = (const float*)d_in[8];
    const float* b2   = (const float*)d_in[9];
    float* out = (float*)d_out;

    char* w = (char*)d_ws;
    auto carve = [&](size_t bytes) {
        void* p = (void*)w;
        w += (bytes + 255) & ~(size_t)255;
        return p;
    };
    int*    csr_raw  = (int*)carve((size_t)TE * 4);            // 3.4 MB
    int*    csr_can  = (int*)carve((size_t)TE * 4);            // 3.4 MB (canonical)
    int*    offs     = (int*)carve((size_t)(NN + 1) * 4);
    int*    deg      = (int*)carve((size_t)NN * 4);
    int*    chunkoff = (int*)carve(256 * 4);
    float*  a_src1   = (float*)carve((size_t)NN * 16 * 4);     // 3.2 MB
    float*  a_dst1   = (float*)carve((size_t)NN * 16 * 4);     // 3.2 MB
    bf16*   h1       = (bf16*)carve((size_t)NN * 256 * 2);     // 25.6 MB
    bf16*   out1     = (bf16*)carve((size_t)NN * 256 * 2);     // 25.6 MB
    // layer-2 buffers alias h1 (dead after agg1)
    char*   l2base   = (char*)h1;
    bf16*   h2       = (bf16*)l2base;
    float*  a_src2   = (float*)(l2base + (size_t)NN * 64 * 2);
    float*  a_dst2   = a_src2 + NN;

    hipMemsetAsync(deg, 0, (size_t)NN * 4, stream);

    const int pgrid = ((TE + 1) / 2 + 255) / 256;
    count_deg_k<<<pgrid, 256, 0, stream>>>(ei, deg);
    scan_chunks_k<<<1, 256, 0, stream>>>(deg, chunkoff);
    scan_within_k<<<NCH, 256, 0, stream>>>(deg, chunkoff, offs);
    fill_csr_k<<<pgrid, 256, 0, stream>>>(ei, offs, deg, csr_raw);
    rank_csr_k<<<(NN + 3) / 4, 256, 0, stream>>>(offs, csr_raw, csr_can);

    gemm1_k<<<(NN + 31) / 32, 256, 0, stream>>>(x, W1, asr1, ads1, h1, a_src1, a_dst1);
    agg1_k<<<NN / 4, 256, 0, stream>>>(offs, csr_can, a_src1, a_dst1, h1, b1, out1);
    gemm2_k<<<(NN + 63) / 64, 256, 0, stream>>>(out1, W2, asr2, ads2, h2, a_src2, a_dst2);
    agg2_k<<<(NN + 3) / 4, 256, 0, stream>>>(offs, csr_can, a_src2, a_dst2, h2, b2, out);
}